// Round 1
// baseline (1469.466 us; speedup 1.0000x reference)
//
#include <hip/hip_runtime.h>
#include <hip/hip_bf16.h>
#include <cmath>

typedef __bf16 bf16;
typedef __attribute__((ext_vector_type(8))) __bf16 bf16x8;
typedef __attribute__((ext_vector_type(4))) __bf16 bf16x4;
typedef __attribute__((ext_vector_type(4))) float f32x4;

#define TEMPC 65.0f
#define EPSC 1e-6f

// ---------------- f32 -> bf16 convert ----------------
__global__ void conv_kernel(const float* __restrict__ s, bf16* __restrict__ d, int n)
{
    int i = (blockIdx.x * blockDim.x + threadIdx.x) * 4;
    const int stride = gridDim.x * blockDim.x * 4;
    for (; i < n; i += stride) {
        const float4 v = *(const float4*)(s + i);
        bf16x4 o;
        o[0] = (bf16)v.x; o[1] = (bf16)v.y; o[2] = (bf16)v.z; o[3] = (bf16)v.w;
        *(bf16x4*)(d + i) = o;
    }
}

// ---------------- shared MFMA GEMM: gathered-A [128 rows] @ W^T ----------------
// MODE 0: store XW = acc + b_ih   (A rows = emb[data[r]])
// MODE 1: s-loop over 10 samples; epilogue: tanh(acc + Ust) -> dist atomicAdd
template<int MODE>
__global__ __launch_bounds__(256)
void gemm_kernel(const int* __restrict__ idx, const bf16* __restrict__ emb,
                 const bf16* __restrict__ Wmat, const float* __restrict__ bih,
                 const float* __restrict__ Ust, const bf16* __restrict__ prevb,
                 float* __restrict__ XWout, float* __restrict__ dist)
{
    // 128x32 bf16 tiles, rows padded to 80 bytes (~2-way LDS banking on b128 reads)
    __shared__ __align__(16) char smem[2 * 128 * 80];
    char* As = smem;
    char* Bs = smem + 128 * 80;

    const int tid = threadIdx.x;
    const int l  = tid & 63;
    const int w  = tid >> 6;
    const int wr = w >> 1, wc = w & 1;          // wave quadrant (64x64)
    const int mbase = (blockIdx.x >> 3) * 128;
    const int nbase = (blockIdx.x & 7) * 128;

    // staging: 2 threads per row, 2x16B chunks each (row = 64B of bf16)
    const int srow = tid >> 1;
    const int c0   = (tid & 1) * 2;
    char* AsW = As + srow * 80 + c0 * 16;
    char* BsW = Bs + srow * 80 + c0 * 16;
    const char* Bsrc = (const char*)Wmat + (size_t)(nbase + srow) * 2048 + c0 * 16;

    // fragment read offset: row=(l&15), k-chunk=(l>>4)*16B
    const int lo = (l & 15) * 80 + (l >> 4) * 16;
    const char* ArdBase = As + (wr * 64) * 80 + lo;
    const char* BrdBase = Bs + (wc * 64) * 80 + lo;

    const int NS = MODE ? 10 : 1;
    for (int s = 0; s < NS; ++s) {
        const int grow = idx[s * 8192 + mbase + srow];
        const char* Asrc = (const char*)emb + (size_t)grow * 2048 + c0 * 16;

        f32x4 acc[4][4] = {};
        for (int k0 = 0; k0 < 1024; k0 += 32) {
            bf16x8 av0 = *(const bf16x8*)(Asrc + k0 * 2);
            bf16x8 av1 = *(const bf16x8*)(Asrc + k0 * 2 + 16);
            bf16x8 bv0 = *(const bf16x8*)(Bsrc + k0 * 2);
            bf16x8 bv1 = *(const bf16x8*)(Bsrc + k0 * 2 + 16);
            __syncthreads();                    // protect prior iter's LDS reads
            *(bf16x8*)(AsW)      = av0;
            *(bf16x8*)(AsW + 16) = av1;
            *(bf16x8*)(BsW)      = bv0;
            *(bf16x8*)(BsW + 16) = bv1;
            __syncthreads();
            bf16x8 af[4], bfr[4];
            #pragma unroll
            for (int mt = 0; mt < 4; ++mt) af[mt]  = *(const bf16x8*)(ArdBase + mt * 16 * 80);
            #pragma unroll
            for (int nt = 0; nt < 4; ++nt) bfr[nt] = *(const bf16x8*)(BrdBase + nt * 16 * 80);
            #pragma unroll
            for (int mt = 0; mt < 4; ++mt)
                #pragma unroll
                for (int nt = 0; nt < 4; ++nt)
                    acc[mt][nt] = __builtin_amdgcn_mfma_f32_16x16x32_bf16(af[mt], bfr[nt], acc[mt][nt], 0, 0, 0);
        }

        if (MODE == 0) {
            #pragma unroll
            for (int mt = 0; mt < 4; ++mt)
                #pragma unroll
                for (int nt = 0; nt < 4; ++nt) {
                    const int colg = nbase + wc * 64 + nt * 16 + (l & 15);
                    const float bi = bih[colg];
                    #pragma unroll
                    for (int r = 0; r < 4; ++r) {
                        const int rowg = mbase + wr * 64 + mt * 16 + (l >> 4) * 4 + r;
                        XWout[(size_t)rowg * 1024 + colg] = acc[mt][nt][r] + bi;
                    }
                }
        } else {
            #pragma unroll
            for (int mt = 0; mt < 4; ++mt)
                #pragma unroll
                for (int r = 0; r < 4; ++r) {
                    const int rowg = mbase + wr * 64 + mt * 16 + (l >> 4) * 4 + r;
                    float p = 0.f;
                    #pragma unroll
                    for (int nt = 0; nt < 4; ++nt) {
                        const int colg = nbase + wc * 64 + nt * 16 + (l & 15);
                        const size_t e = (size_t)rowg * 1024 + colg;
                        const float o = tanhf(acc[mt][nt][r] + Ust[e]);
                        const float d = (float)prevb[e] - o + EPSC;
                        p += d * d;
                    }
                    #pragma unroll
                    for (int off = 1; off < 16; off <<= 1)
                        p += __shfl_xor(p, off, 16);
                    if ((l & 15) == 0) atomicAdd(&dist[s * 8192 + rowg], p);
                }
        }
    }
}

// ---------------- one RNN step: h_{t+1} = tanh(XW_b[t] + h_t @ W_hh^T + b_hh) ----------------
// grid 256 (4 b-tiles x 64 j-tiles), 1 wave per block; fragments straight from L2.
__global__ __launch_bounds__(64)
void rnn_step(bf16* __restrict__ raw, const bf16* __restrict__ Whh,
              const float* __restrict__ XWb, const float* __restrict__ bih,
              const float* __restrict__ bhh, float* __restrict__ Ust, int t)
{
    const int l  = threadIdx.x;
    const int jt = blockIdx.x & 63;
    const int bt = blockIdx.x >> 6;
    const bf16* A = raw + (size_t)t * 65536;
    const int arow = bt * 16 + (l & 15);
    const int brow = jt * 16 + (l & 15);
    const int koff = (l >> 4) * 8;
    const bf16* Ap = A   + (size_t)arow * 1024 + koff;
    const bf16* Bp = Whh + (size_t)brow * 1024 + koff;
    f32x4 acc = {0.f, 0.f, 0.f, 0.f};
    #pragma unroll 8
    for (int k0 = 0; k0 < 1024; k0 += 32) {
        bf16x8 af  = *(const bf16x8*)(Ap + k0);
        bf16x8 bfr = *(const bf16x8*)(Bp + k0);
        acc = __builtin_amdgcn_mfma_f32_16x16x32_bf16(af, bfr, acc, 0, 0, 0);
    }
    const int j = jt * 16 + (l & 15);
    const float bi = bih[j], bh = bhh[j];
    bf16* rawN = raw + (size_t)(t + 1) * 65536;
    #pragma unroll
    for (int r = 0; r < 4; ++r) {
        const int b = bt * 16 + (l >> 4) * 4 + r;
        const float V = acc[r] + bh;                 // h_t @ W_hh^T + b_hh
        const size_t e = (size_t)(t * 64 + b) * 1024 + j;
        const float h = tanhf(XWb[e] + V);           // XWb already holds +b_ih
        rawN[(size_t)b * 1024 + j] = (bf16)h;
        Ust[e] = V + bi;                             // hiddens_U + b_ih, reused in phase D
    }
}

// ---------------- pos term: (65/128) * sum (raw[t]-raw[t+1]+eps)^2 ----------------
__global__ void pos_kernel(const bf16* __restrict__ raw, float* __restrict__ lacc)
{
    float s = 0.f;
    const int NV = (128 * 64 * 1024) / 8;
    for (int i = blockIdx.x * blockDim.x + threadIdx.x; i < NV; i += gridDim.x * blockDim.x) {
        bf16x8 a = *(const bf16x8*)(raw + (size_t)i * 8);
        bf16x8 b = *(const bf16x8*)(raw + (size_t)i * 8 + 65536);
        #pragma unroll
        for (int j = 0; j < 8; ++j) {
            const float d = (float)a[j] - (float)b[j] + EPSC;
            s += d * d;
        }
    }
    #pragma unroll
    for (int off = 32; off > 0; off >>= 1) s += __shfl_down(s, off, 64);
    if ((threadIdx.x & 63) == 0) atomicAdd(lacc, s * (TEMPC / 128.f));
}

// ---------------- finalize: clip, exp, log, total ----------------
__global__ __launch_bounds__(1024)
void finalize_kernel(const float* __restrict__ dist, const float* __restrict__ lacc,
                     float* __restrict__ out)
{
    float s = 0.f;
    for (int r = threadIdx.x; r < 8192; r += 1024) {
        float se = 0.f;
        #pragma unroll
        for (int k = 0; k < 10; ++k) {
            float dd = dist[k * 8192 + r];
            dd = fminf(fmaxf(dd, 0.f), 0.01f);
            se += expf(-dd);
        }
        s += logf(se * (1.f / 8192.f) + EPSC);
    }
    #pragma unroll
    for (int off = 32; off > 0; off >>= 1) s += __shfl_down(s, off, 64);
    __shared__ float red[16];
    const int wave = threadIdx.x >> 6;
    if ((threadIdx.x & 63) == 0) red[wave] = s;
    __syncthreads();
    if (threadIdx.x == 0) {
        float tot = 0.f;
        #pragma unroll
        for (int i = 0; i < 16; ++i) tot += red[i];
        out[0] = tot + lacc[0];
    }
}

extern "C" void kernel_launch(void* const* d_in, const int* in_sizes, int n_in,
                              void* d_out, int out_size, void* d_ws, size_t ws_size,
                              hipStream_t stream)
{
    const int*   data    = (const int*)d_in[0];   // [128*64]
    const int*   samples = (const int*)d_in[1];   // [10*8192]
    const float* emb     = (const float*)d_in[2]; // [32000*1024]
    const float* Wih     = (const float*)d_in[3]; // [1024*1024]
    const float* bih     = (const float*)d_in[4]; // [1024]
    const float* Whh     = (const float*)d_in[5]; // [1024*1024]
    const float* bhh     = (const float*)d_in[6]; // [1024]

    char* ws = (char*)d_ws;
    size_t off = 0;
    auto alloc = [&](size_t bytes) { void* p = ws + off; off += (bytes + 255) & ~(size_t)255; return p; };
    bf16*  emb_b = (bf16*)alloc((size_t)32000 * 1024 * 2);
    bf16*  Wih_b = (bf16*)alloc((size_t)1024 * 1024 * 2);
    bf16*  Whh_b = (bf16*)alloc((size_t)1024 * 1024 * 2);
    float* XWb   = (float*)alloc((size_t)8192 * 1024 * 4);
    float* Ust   = (float*)alloc((size_t)8192 * 1024 * 4);
    bf16*  raw   = (bf16*)alloc((size_t)129 * 64 * 1024 * 2);
    float* dist  = (float*)alloc((size_t)10 * 8192 * 4);
    float* lacc  = (float*)alloc(256);

    hipMemsetAsync(raw,  0, 64 * 1024 * 2, stream);   // h0 = 0 (raw[0])
    hipMemsetAsync(dist, 0, 10 * 8192 * 4, stream);
    hipMemsetAsync(lacc, 0, 256, stream);

    conv_kernel<<<2048, 256, 0, stream>>>(emb, emb_b, 32000 * 1024);
    conv_kernel<<<512, 256, 0, stream>>>(Wih, Wih_b, 1024 * 1024);
    conv_kernel<<<512, 256, 0, stream>>>(Whh, Whh_b, 1024 * 1024);

    // Phase A: XWb = emb[data] @ Wih^T + bih
    gemm_kernel<0><<<512, 256, 0, stream>>>(data, emb_b, Wih_b, bih,
                                            nullptr, nullptr, XWb, nullptr);
    // Phase B: 128 sequential RNN steps (writes raw[t+1], Ust[t])
    for (int t = 0; t < 128; ++t)
        rnn_step<<<256, 64, 0, stream>>>(raw, Whh_b, XWb, bih, bhh, Ust, t);

    // pos term
    pos_kernel<<<512, 256, 0, stream>>>(raw, lacc);

    // Phase D: sampled negatives GEMM + fused dist epilogue
    gemm_kernel<1><<<512, 256, 0, stream>>>(samples, emb_b, Wih_b, bih,
                                            Ust, raw, nullptr, dist);

    finalize_kernel<<<1, 1024, 0, stream>>>(dist, lacc, (float*)d_out);
}